// Round 4
// baseline (872.318 us; speedup 1.0000x reference)
//
#include <hip/hip_runtime.h>

#pragma clang fp contract(off)

// TV-L1 optical flow inner scale (TVNet), B=8, H=W=480, 5 warps x 5 iters.
// Outputs: u1, u2, rho concatenated in d_out (3*N floats).
// All fp arithmetic mirrors the JAX-f32 reference op-for-op: no FMA
// contraction, left-to-right association, and JAX-style float32 linspace
// (delta = (stop-start)/div in f32, out = start + iota*delta in f32, no
// endpoint forcing). The STN warp has O(1) discontinuities at the clip
// lines, so floor(x) decisions must match the oracle bitwise.

constexpr int B = 8, H = 480, W = 480;
constexpr int HW = H * W;
constexpr int N = B * HW;

constexpr float THETA = (float)0.3;
constexpr float L_T  = (float)(0.15 * 0.3);   // python f64 product, cast f32
constexpr float TAUT = (float)(0.25 / 0.3);
constexpr float EPSF = (float)1e-12;

#define TPB 256
#define GRD ((N + TPB - 1) / TPB)

__global__ __launch_bounds__(TPB) void k_init(
    const float* __restrict__ u1_in, const float* __restrict__ u2_in,
    float* __restrict__ u1, float* __restrict__ u2,
    float* __restrict__ p11, float* __restrict__ p12,
    float* __restrict__ p21, float* __restrict__ p22) {
  int i = blockIdx.x * TPB + threadIdx.x;
  if (i >= N) return;
  u1[i] = u1_in[i];
  u2[i] = u2_in[i];
  p11[i] = 0.f; p12[i] = 0.f; p21[i] = 0.f; p22[i] = 0.f;
}

// Warp x2 and its centered gradients by flow (u1,u2); emit dxw, dyw, rho_c.
__global__ __launch_bounds__(TPB) void k_warp(
    const float* __restrict__ x1, const float* __restrict__ x2,
    const float* __restrict__ u1, const float* __restrict__ u2,
    float* __restrict__ dxw_o, float* __restrict__ dyw_o,
    float* __restrict__ rhoc_o) {
  int i = blockIdx.x * TPB + threadIdx.x;
  if (i >= N) return;
  int b = i / HW;
  int r = i - b * HW;
  int h = r / W;
  int w = r - h * W;

  float u = u1[i], v = u2[i];

  // JAX f32 linspace: delta = 2.0f/479.0f (f32 div), out = -1.0f + i*delta.
  // No endpoint forcing (matches jnp.linspace implementation).
  const float step = 2.0f / 479.0f;
  float gx = -1.0f + (float)w * step;
  float gy = -1.0f + (float)h * step;

  // x = (gx + u*(2/W) + 1) * (W/2), f32 left-to-right; scalar 2.0/480 is a
  // python-f64 weak scalar cast to f32.
  float x = ((gx + u * (float)(2.0 / 480.0)) + 1.0f) * 240.0f;
  float y = ((gy + v * (float)(2.0 / 480.0)) + 1.0f) * 240.0f;

  float fx = floorf(x), fy = floorf(y);
  int x0 = (int)fx, y0 = (int)fy;
  int x0i = min(max(x0, 0), W - 1);
  int x1i = min(max(x0 + 1, 0), W - 1);
  int y0i = min(max(y0, 0), H - 1);
  int y1i = min(max(y0 + 1, 0), H - 1);
  float x0f = (float)x0i, x1f = (float)x1i, y0f = (float)y0i, y1f = (float)y1i;
  // weights from CLIPPED integer coords (cancel out of range — matches ref)
  float wa = (x1f - x) * (y1f - y);
  float wb = (x1f - x) * (y - y0f);
  float wc = (x - x0f) * (y1f - y);
  float wd = (x - x0f) * (y - y0f);

  const float* __restrict__ im = x2 + (size_t)b * HW;
  auto at = [&](int yy, int xx) -> float { return im[yy * W + xx]; };
  // centered gradient with clamped indices == reference one-sided boundary
  auto dxc = [&](int yy, int xx) -> float {
    int xm = max(xx - 1, 0), xp = min(xx + 1, W - 1);
    return 0.5f * (at(yy, xp) - at(yy, xm));
  };
  auto dyc = [&](int yy, int xx) -> float {
    int ym = max(yy - 1, 0), yp = min(yy + 1, H - 1);
    return 0.5f * (at(yp, xx) - at(ym, xx));
  };

  // np order: ((wa*Ia + wb*Ib) + wc*Ic) + wd*Id
  float x2w = ((wa * at(y0i, x0i) + wb * at(y1i, x0i)) + wc * at(y0i, x1i)) + wd * at(y1i, x1i);
  float dxw = ((wa * dxc(y0i, x0i) + wb * dxc(y1i, x0i)) + wc * dxc(y0i, x1i)) + wd * dxc(y1i, x1i);
  float dyw = ((wa * dyc(y0i, x0i) + wb * dyc(y1i, x0i)) + wc * dyc(y0i, x1i)) + wd * dyc(y1i, x1i);

  dxw_o[i] = dxw;
  dyw_o[i] = dyw;
  rhoc_o[i] = ((x2w - dxw * u) - dyw * v) - x1[i];
}

// rho / threshold / v, then u = v + THETA * div(p)
__global__ __launch_bounds__(TPB) void k_update_u(
    const float* __restrict__ dxw, const float* __restrict__ dyw,
    const float* __restrict__ rhoc,
    const float* __restrict__ p11, const float* __restrict__ p12,
    const float* __restrict__ p21, const float* __restrict__ p22,
    float* __restrict__ u1, float* __restrict__ u2,
    float* __restrict__ rho_out, int write_rho) {
  int i = blockIdx.x * TPB + threadIdx.x;
  if (i >= N) return;
  int b = i / HW;
  int r = i - b * HW;
  int h = r / W;
  int w = r - h * W;

  float dx = dxw[i], dy = dyw[i];
  float u = u1[i], v = u2[i];
  float rho = ((rhoc[i] + dx * u) + dy * v) + EPSF;
  float grad = (dx * dx + dy * dy) + EPSF;
  float lt_g = L_T * grad;
  float s;
  if (rho < -lt_g)      s = L_T;
  else if (rho > lt_g)  s = -L_T;
  else if (grad > EPSF) s = (-rho) / grad;
  else                  s = 0.f;
  float v1 = s * dx + u;
  float v2 = s * dy + v;

  const float* __restrict__ P11 = p11 + (size_t)b * HW;
  const float* __restrict__ P12 = p12 + (size_t)b * HW;
  const float* __restrict__ P21 = p21 + (size_t)b * HW;
  const float* __restrict__ P22 = p22 + (size_t)b * HW;

  // forward_divergence: backward diff, first col/row = p, last = -p[-2]
  float dvx1, dvy1, dvx2, dvy2;
  if (w == 0)          dvx1 = P11[r];
  else if (w == W - 1) dvx1 = -P11[r - 1];
  else                 dvx1 = P11[r] - P11[r - 1];
  if (h == 0)          dvy1 = P12[r];
  else if (h == H - 1) dvy1 = -P12[r - W];
  else                 dvy1 = P12[r] - P12[r - W];
  if (w == 0)          dvx2 = P21[r];
  else if (w == W - 1) dvx2 = -P21[r - 1];
  else                 dvx2 = P21[r] - P21[r - 1];
  if (h == 0)          dvy2 = P22[r];
  else if (h == H - 1) dvy2 = -P22[r - W];
  else                 dvy2 = P22[r] - P22[r - W];

  u1[i] = v1 + THETA * (dvx1 + dvy1);
  u2[i] = v2 + THETA * (dvx2 + dvy2);
  if (write_rho) rho_out[i] = rho;
}

// forward gradient of u, then p = (p + taut*grad(u)) / (1 + taut*|grad(u)|)
__global__ __launch_bounds__(TPB) void k_update_p(
    const float* __restrict__ u1, const float* __restrict__ u2,
    float* __restrict__ p11, float* __restrict__ p12,
    float* __restrict__ p21, float* __restrict__ p22) {
  int i = blockIdx.x * TPB + threadIdx.x;
  if (i >= N) return;
  int b = i / HW;
  int r = i - b * HW;
  int h = r / W;
  int w = r - h * W;

  const float* __restrict__ U1 = u1 + (size_t)b * HW;
  const float* __restrict__ U2 = u2 + (size_t)b * HW;
  float u1c = U1[r], u2c = U2[r];
  float u1x = (w < W - 1) ? U1[r + 1] - u1c : 0.f;
  float u1y = (h < H - 1) ? U1[r + W] - u1c : 0.f;
  float u2x = (w < W - 1) ? U2[r + 1] - u2c : 0.f;
  float u2y = (h < H - 1) ? U2[r + W] - u2c : 0.f;

  float n1 = 1.0f + TAUT * sqrtf((u1x * u1x + u1y * u1y) + EPSF);
  float n2 = 1.0f + TAUT * sqrtf((u2x * u2x + u2y * u2y) + EPSF);
  p11[i] = (p11[i] + TAUT * u1x) / n1;
  p12[i] = (p12[i] + TAUT * u1y) / n1;
  p21[i] = (p21[i] + TAUT * u2x) / n2;
  p22[i] = (p22[i] + TAUT * u2y) / n2;
}

extern "C" void kernel_launch(void* const* d_in, const int* in_sizes, int n_in,
                              void* d_out, int out_size, void* d_ws, size_t ws_size,
                              hipStream_t stream) {
  const float* x1 = (const float*)d_in[0];
  const float* x2 = (const float*)d_in[1];
  const float* u1_in = (const float*)d_in[2];
  const float* u2_in = (const float*)d_in[3];

  float* u1 = (float*)d_out;
  float* u2 = u1 + (size_t)N;
  float* rho = u1 + (size_t)2 * N;

  float* ws = (float*)d_ws;
  float* dxw  = ws;
  float* dyw  = ws + (size_t)N;
  float* rhoc = ws + (size_t)2 * N;
  float* p11  = ws + (size_t)3 * N;
  float* p12  = ws + (size_t)4 * N;
  float* p21  = ws + (size_t)5 * N;
  float* p22  = ws + (size_t)6 * N;

  dim3 blk(TPB), grd(GRD);
  k_init<<<grd, blk, 0, stream>>>(u1_in, u2_in, u1, u2, p11, p12, p21, p22);
  for (int wp = 0; wp < 5; ++wp) {
    k_warp<<<grd, blk, 0, stream>>>(x1, x2, u1, u2, dxw, dyw, rhoc);
    for (int it = 0; it < 5; ++it) {
      int wr = (wp == 4 && it == 4) ? 1 : 0;
      k_update_u<<<grd, blk, 0, stream>>>(dxw, dyw, rhoc, p11, p12, p21, p22,
                                          u1, u2, rho, wr);
      k_update_p<<<grd, blk, 0, stream>>>(u1, u2, p11, p12, p21, p22);
    }
  }
}

// Round 5
// 706.235 us; speedup vs baseline: 1.2352x; 1.2352x over previous
//
#include <hip/hip_runtime.h>

#pragma clang fp contract(off)

// TV-L1 optical flow inner scale (TVNet), B=8, H=W=480, 5 warps x 5 iters.
// Fused: one kernel per warp step (warp + 5 inner iterations) with
// spatio-temporal tiling. Region 64x40 per block = tile 54x30 + halo 5.
// State u1,u2,p11..p22 lives in LDS; warp constants (dxw,dyw,rho_c) and
// own-pixel state in registers (10 px/thread, statically indexed).
// All per-pixel fp arithmetic is op-for-op identical to the previously
// passing version (JAX-f32 linspace, no FMA contraction, left-to-right
// association) — halo recompute yields bit-identical values.

constexpr int B = 8, H = 480, W = 480;
constexpr int HW = H * W;
constexpr int N = B * HW;

constexpr float THETA = (float)0.3;
constexpr float L_T  = (float)(0.15 * 0.3);   // python f64 product, cast f32
constexpr float TAUT = (float)(0.25 / 0.3);
constexpr float EPSF = (float)1e-12;

#define RW 64              // region width  (LDS tile incl. halo)
#define RH 40              // region height
#define HALO 5
#define TW (RW - 2*HALO)   // 54 output tile width
#define TH (RH - 2*HALO)   // 30 output tile height
#define NTX 9              // ceil(480/54)
#define NTY 16             // 480/30
#define NPX (RW*RH/256)    // 10 pixels per thread

__global__ __launch_bounds__(256, 2) void k_fused(
    const float* __restrict__ x1, const float* __restrict__ x2,
    const float* __restrict__ u1In, const float* __restrict__ u2In,
    const float* __restrict__ pIn,          // 4 arrays of N, or nullptr (=0)
    float* __restrict__ u1Out, float* __restrict__ u2Out,
    float* __restrict__ pOut,               // 4 arrays of N
    float* __restrict__ rhoOut, int lastWarp)
{
  __shared__ float su1[RH][RW], su2[RH][RW];
  __shared__ float sp11[RH][RW], sp12[RH][RW], sp21[RH][RW], sp22[RH][RW];

  int blk = blockIdx.x;
  int bx = blk % NTX;
  int by = (blk / NTX) % NTY;
  int b  = blk / (NTX * NTY);
  int ox = bx * TW - HALO;
  int oy = by * TH - HALO;

  int tid = threadIdx.x;
  int lx  = tid & (RW - 1);
  int lyb = tid >> 6;           // 0..3, rows lyb + 4k

  const float* __restrict__ im = x2 + b * HW;
  const int base = b * HW;

  float cdx[NPX], cdy[NPX], crc[NPX];         // dxw, dyw, rho_c
  float ru1[NPX], ru2[NPX];                   // own-pixel u
  float rp11[NPX], rp12[NPX], rp21[NPX], rp22[NPX];  // own-pixel p

  // ---- warp stage: bilinear warp of x2 & its centered gradients ----
#pragma unroll
  for (int k = 0; k < NPX; ++k) {
    int ly = lyb + 4 * k;
    int px = ox + lx, py = oy + ly;
    bool valid = (px >= 0 && px < W && py >= 0 && py < H);
    if (valid) {
      int gi = base + py * W + px;
      float u = u1In[gi], v = u2In[gi];
      // JAX f32 linspace: delta = 2/479 (f32 div), out = -1 + i*delta
      const float step = 2.0f / 479.0f;
      float gx = -1.0f + (float)px * step;
      float gy = -1.0f + (float)py * step;
      float X = ((gx + u * (float)(2.0 / 480.0)) + 1.0f) * 240.0f;
      float Y = ((gy + v * (float)(2.0 / 480.0)) + 1.0f) * 240.0f;
      float fX = floorf(X), fY = floorf(Y);
      int ix = (int)fX, iy = (int)fY;
      int x0i = min(max(ix, 0), W - 1);
      int x1i = min(max(ix + 1, 0), W - 1);
      int y0i = min(max(iy, 0), H - 1);
      int y1i = min(max(iy + 1, 0), H - 1);
      float x0f = (float)x0i, x1f = (float)x1i;
      float y0f = (float)y0i, y1f = (float)y1i;
      float wa = (x1f - X) * (y1f - Y);
      float wb = (x1f - X) * (Y - y0f);
      float wc = (X - x0f) * (y1f - Y);
      float wd = (X - x0f) * (Y - y0f);
      auto at = [&](int yy, int xx) -> float { return im[yy * W + xx]; };
      auto dxc = [&](int yy, int xx) -> float {
        int xm = max(xx - 1, 0), xp = min(xx + 1, W - 1);
        return 0.5f * (at(yy, xp) - at(yy, xm));
      };
      auto dyc = [&](int yy, int xx) -> float {
        int ym = max(yy - 1, 0), yp = min(yy + 1, H - 1);
        return 0.5f * (at(yp, xx) - at(ym, xx));
      };
      float x2w = ((wa * at(y0i, x0i) + wb * at(y1i, x0i)) + wc * at(y0i, x1i)) + wd * at(y1i, x1i);
      float dxw = ((wa * dxc(y0i, x0i) + wb * dxc(y1i, x0i)) + wc * dxc(y0i, x1i)) + wd * dxc(y1i, x1i);
      float dyw = ((wa * dyc(y0i, x0i) + wb * dyc(y1i, x0i)) + wc * dyc(y0i, x1i)) + wd * dyc(y1i, x1i);
      cdx[k] = dxw; cdy[k] = dyw;
      crc[k] = ((x2w - dxw * u) - dyw * v) - x1[gi];
      ru1[k] = u; ru2[k] = v;
      float q11, q12, q21, q22;
      if (pIn) {
        q11 = pIn[0 * N + gi]; q12 = pIn[1 * N + gi];
        q21 = pIn[2 * N + gi]; q22 = pIn[3 * N + gi];
      } else { q11 = 0.f; q12 = 0.f; q21 = 0.f; q22 = 0.f; }
      rp11[k] = q11; rp12[k] = q12; rp21[k] = q21; rp22[k] = q22;
      su1[ly][lx] = u;   su2[ly][lx] = v;
      sp11[ly][lx] = q11; sp12[ly][lx] = q12;
      sp21[ly][lx] = q21; sp22[ly][lx] = q22;
    }
  }
  __syncthreads();

  // ---- 5 inner iterations, validity boxes shrink by 1/side/iter except
  //      where the region edge is at/past the image boundary ----
  for (int t = 1; t <= 5; ++t) {
    int ulox = ox + t; if (ulox < 0) ulox = 0;
    int uloy = oy + t; if (uloy < 0) uloy = 0;
    int uhix = (ox + RW >= W) ? W : (ox + RW + 1 - t);
    int uhiy = (oy + RH >= H) ? H : (oy + RH + 1 - t);

    // u-phase: reads p (regs + LDS left/up), writes u (regs + LDS)
#pragma unroll
    for (int k = 0; k < NPX; ++k) {
      int ly = lyb + 4 * k;
      int px = ox + lx, py = oy + ly;
      if (px >= ulox && px < uhix && py >= uloy && py < uhiy) {
        float dx = cdx[k], dy = cdy[k];
        float u = ru1[k], v = ru2[k];
        float rho = ((crc[k] + dx * u) + dy * v) + EPSF;
        float grad = (dx * dx + dy * dy) + EPSF;
        float lt_g = L_T * grad;
        float s;
        if (rho < -lt_g)      s = L_T;
        else if (rho > lt_g)  s = -L_T;
        else if (grad > EPSF) s = (-rho) / grad;
        else                  s = 0.f;
        float v1 = s * dx + u;
        float v2 = s * dy + v;
        float dvx1, dvy1, dvx2, dvy2;
        if (px == 0)          dvx1 = rp11[k];
        else if (px == W - 1) dvx1 = -sp11[ly][lx - 1];
        else                  dvx1 = rp11[k] - sp11[ly][lx - 1];
        if (py == 0)          dvy1 = rp12[k];
        else if (py == H - 1) dvy1 = -sp12[ly - 1][lx];
        else                  dvy1 = rp12[k] - sp12[ly - 1][lx];
        if (px == 0)          dvx2 = rp21[k];
        else if (px == W - 1) dvx2 = -sp21[ly][lx - 1];
        else                  dvx2 = rp21[k] - sp21[ly][lx - 1];
        if (py == 0)          dvy2 = rp22[k];
        else if (py == H - 1) dvy2 = -sp22[ly - 1][lx];
        else                  dvy2 = rp22[k] - sp22[ly - 1][lx];
        float nu1 = v1 + THETA * (dvx1 + dvy1);
        float nu2 = v2 + THETA * (dvx2 + dvy2);
        ru1[k] = nu1; ru2[k] = nu2;
        su1[ly][lx] = nu1; su2[ly][lx] = nu2;
        if (lastWarp && t == 5) {
          int tx0 = bx * TW, ty0 = by * TH;
          if (px >= tx0 && px < min(tx0 + TW, W) &&
              py >= ty0 && py < min(ty0 + TH, H))
            rhoOut[base + py * W + px] = rho;
        }
      }
    }
    __syncthreads();

    // p-phase: reads u (regs + LDS right/down), writes p (regs + LDS).
    // Skipped on the last warp's final iteration (p^5 is dead there).
    if (!(lastWarp && t == 5)) {
      int phix = (ox + RW >= W) ? W : (ox + RW - t);
      int phiy = (oy + RH >= H) ? H : (oy + RH - t);
#pragma unroll
      for (int k = 0; k < NPX; ++k) {
        int ly = lyb + 4 * k;
        int px = ox + lx, py = oy + ly;
        if (px >= ulox && px < phix && py >= uloy && py < phiy) {
          float u1c = ru1[k], u2c = ru2[k];
          float u1x = (px < W - 1) ? su1[ly][lx + 1] - u1c : 0.f;
          float u1y = (py < H - 1) ? su1[ly + 1][lx] - u1c : 0.f;
          float u2x = (px < W - 1) ? su2[ly][lx + 1] - u2c : 0.f;
          float u2y = (py < H - 1) ? su2[ly + 1][lx] - u2c : 0.f;
          float n1 = 1.0f + TAUT * sqrtf((u1x * u1x + u1y * u1y) + EPSF);
          float n2 = 1.0f + TAUT * sqrtf((u2x * u2x + u2y * u2y) + EPSF);
          float np11 = (rp11[k] + TAUT * u1x) / n1;
          float np12 = (rp12[k] + TAUT * u1y) / n1;
          float np21 = (rp21[k] + TAUT * u2x) / n2;
          float np22 = (rp22[k] + TAUT * u2y) / n2;
          rp11[k] = np11; rp12[k] = np12; rp21[k] = np21; rp22[k] = np22;
          sp11[ly][lx] = np11; sp12[ly][lx] = np12;
          sp21[ly][lx] = np21; sp22[ly][lx] = np22;
        }
      }
    }
    __syncthreads();
  }

  // ---- write-out: tile pixels only (tiles partition the image) ----
  int tx0 = bx * TW, ty0 = by * TH;
  int tx1 = min(tx0 + TW, W), ty1 = min(ty0 + TH, H);
#pragma unroll
  for (int k = 0; k < NPX; ++k) {
    int ly = lyb + 4 * k;
    int px = ox + lx, py = oy + ly;
    if (px >= tx0 && px < tx1 && py >= ty0 && py < ty1) {
      int gi = base + py * W + px;
      u1Out[gi] = ru1[k];
      u2Out[gi] = ru2[k];
      if (!lastWarp) {
        pOut[0 * N + gi] = rp11[k];
        pOut[1 * N + gi] = rp12[k];
        pOut[2 * N + gi] = rp21[k];
        pOut[3 * N + gi] = rp22[k];
      }
    }
  }
}

extern "C" void kernel_launch(void* const* d_in, const int* in_sizes, int n_in,
                              void* d_out, int out_size, void* d_ws, size_t ws_size,
                              hipStream_t stream) {
  const float* x1 = (const float*)d_in[0];
  const float* x2 = (const float*)d_in[1];
  const float* u1_in = (const float*)d_in[2];
  const float* u2_in = (const float*)d_in[3];

  float* u1o  = (float*)d_out;
  float* u2o  = u1o + (size_t)N;
  float* rhoo = u1o + (size_t)2 * N;

  float* ws  = (float*)d_ws;
  float* uA1 = ws;
  float* uA2 = ws + (size_t)N;
  float* pA  = ws + (size_t)2 * N;   // 4N
  float* uB1 = ws + (size_t)6 * N;
  float* uB2 = ws + (size_t)7 * N;
  float* pB  = ws + (size_t)8 * N;   // 4N (total 12N floats = 88.5 MB)

  dim3 grd(NTX * NTY * B), blk(256);
  k_fused<<<grd, blk, 0, stream>>>(x1, x2, u1_in, u2_in, nullptr, uA1, uA2, pA, rhoo, 0);
  k_fused<<<grd, blk, 0, stream>>>(x1, x2, uA1, uA2, pA, uB1, uB2, pB, rhoo, 0);
  k_fused<<<grd, blk, 0, stream>>>(x1, x2, uB1, uB2, pB, uA1, uA2, pA, rhoo, 0);
  k_fused<<<grd, blk, 0, stream>>>(x1, x2, uA1, uA2, pA, uB1, uB2, pB, rhoo, 0);
  k_fused<<<grd, blk, 0, stream>>>(x1, x2, uB1, uB2, pB, u1o, u2o, pA, rhoo, 1);
}